// Round 5
// baseline (322.589 us; speedup 1.0000x reference)
//
#include <hip/hip_runtime.h>
#include <hip/hip_bf16.h>
#include <float.h>

#define DEVI __device__ __forceinline__

namespace {

constexpr int NB   = 8;     // batch
constexpr int CD   = 256;   // dense channels
constexpr int CS   = 512;   // sparse channels
constexpr int MM   = 4096;  // dense points
constexpr int SS   = 1024;  // sparse points
constexpr int NN   = 4096;  // pcd points
constexpr int KTOT = 768;   // CD + CS
constexpr int OC   = 256;   // output channels
constexpr float KEPS  = 1e-8f;
constexpr float BNEPS = 1e-5f;
constexpr float SLOPE = 0.2f;

// workspace layout (bytes) — total ~68.3 MB
constexpr size_t OFF_SPT  = 0;                           // float [NB][SS][CS]
constexpr size_t SZ_SPT   = (size_t)NB * SS * CS * 4;    // 16,777,216
constexpr size_t OFF_WBF  = OFF_SPT + SZ_SPT;            // bf16  [OC][KTOT]
constexpr size_t SZ_WBF   = (size_t)OC * KTOT * 2;       // 393,216
constexpr size_t OFF_X    = OFF_WBF + SZ_WBF;            // bf16  [NB*MM][KTOT]
constexpr size_t SZ_X     = (size_t)NB * MM * KTOT * 2;  // 50,331,648
constexpr size_t OFF_SSUM = OFF_X + SZ_X;                // float [2*OC]

typedef __attribute__((ext_vector_type(8))) short s16x8;
typedef __attribute__((ext_vector_type(4))) float f32x4;

// float -> bf16 (RNE), returned as raw short
DEVI short f2bf(float f) {
  union { float f; unsigned u; } c; c.f = f;
  unsigned r = c.u + 0x7fffu + ((c.u >> 16) & 1u);
  return (short)(r >> 16);
}

// ------------------------------------------- conv_w -> bf16, + zero stats acc
__global__ void k_wcast(const float* __restrict__ w, short* __restrict__ wbf,
                        float* __restrict__ ssum) {
  int i = blockIdx.x * 256 + threadIdx.x;   // grid covers OC*KTOT exactly
  if (blockIdx.x < 2) ssum[blockIdx.x * 256 + threadIdx.x] = 0.f;
  wbf[i] = f2bf(w[i]);
}

// ------------------------------------------- sparse_data [b][c][s] -> spt [b][s][c]
__global__ void k_transpose(const float* __restrict__ sp, float* __restrict__ spt) {
  __shared__ float t[32][33];
  int blk = blockIdx.x;                 // 8 * 16 * 32 = 4096 blocks
  int st = blk & 31;
  int ct = (blk >> 5) & 15;
  int b  = blk >> 9;
  int tx = threadIdx.x & 31, ty = threadIdx.x >> 5;   // 32 x 8
  int c0 = ct * 32, s0 = st * 32;
#pragma unroll
  for (int r = 0; r < 32; r += 8)
    t[ty + r][tx] = sp[((size_t)(b * CS + c0 + ty + r)) * SS + s0 + tx];
  __syncthreads();
#pragma unroll
  for (int r = 0; r < 32; r += 8)
    spt[((size_t)(b * SS + s0 + ty + r)) * CS + c0 + tx] = t[tx][ty + r];
}

// ---------------------------------------------------------------- KNN + prep
// One block per (b, 64-m tile), XCD-swizzled: b = blk%8 so each XCD works on
// one batch only -> its 2MB spt slice stays L2-resident for phase-3 gathers.
__global__ __launch_bounds__(256) void k_knn_prep(
    const int* __restrict__ didx, const int* __restrict__ sidx,
    const float* __restrict__ pcd, const float* __restrict__ dense,
    const float* __restrict__ spt, short* __restrict__ X,
    float* __restrict__ outIdxF) {
  __shared__ union {
    struct {
      float4 sxyz[SS];                 // 16 KB candidate coords
      float  pd[4][64][3];             // partial top-3 dists
      int    pi[4][64][3];             // partial top-3 idxs
    } k;
    float tile[64][65];                // dense transpose tile (16.6 KB)
  } u;
  __shared__ int   li[192];            // final top-3 idx per m
  __shared__ float lw[192];            // final weights per m

  int blk = blockIdx.x;                // 512 blocks
  int b   = blk & 7;                   // XCD swizzle: same-b -> same XCD
  int m0  = (blk >> 3) << 6;
  int tid = threadIdx.x;
  const float* pb = pcd + (size_t)b * 3 * NN;

  for (int s = tid; s < SS; s += 256) {
    int si = sidx[b * SS + s];
    u.k.sxyz[s] = make_float4(pb[si], pb[NN + si], pb[2 * NN + si], 0.f);
  }
  int p = tid & 63, chunk = tid >> 6;
  int m = m0 + p;
  int di = didx[b * MM + m];
  float px = pb[di], py = pb[NN + di], pz = pb[2 * NN + di];
  if (chunk == 0) outIdxF[b * MM + m] = (float)di;   // output 1
  __syncthreads();

  {
    float d0 = FLT_MAX, d1 = FLT_MAX, d2 = FLT_MAX;
    int   i0 = 0, i1 = 0, i2 = 0;
    int s0c = chunk << 8;
#pragma unroll 4
    for (int t = 0; t < 256; ++t) {
      int s = s0c + t;
      float4 c = u.k.sxyz[s];
      float dx = c.x - px, dy = c.y - py, dz = c.z - pz;
      float d  = dx * dx + dy * dy + dz * dz;
      bool lt0 = d < d0, lt1 = d < d1, lt2 = d < d2;
      d2 = lt1 ? d1 : (lt2 ? d : d2);  i2 = lt1 ? i1 : (lt2 ? s : i2);
      d1 = lt0 ? d0 : (lt1 ? d : d1);  i1 = lt0 ? i0 : (lt1 ? s : i1);
      d0 = lt0 ? d  : d0;              i0 = lt0 ? s : i0;
    }
    u.k.pd[chunk][p][0] = d0; u.k.pd[chunk][p][1] = d1; u.k.pd[chunk][p][2] = d2;
    u.k.pi[chunk][p][0] = i0; u.k.pi[chunk][p][1] = i1; u.k.pi[chunk][p][2] = i2;
  }
  __syncthreads();

  if (tid < 64) {
    float e0 = FLT_MAX, e1 = FLT_MAX, e2 = FLT_MAX;
    int   j0 = 0, j1 = 0, j2 = 0;
#pragma unroll
    for (int c = 0; c < 4; ++c)
#pragma unroll
      for (int r = 0; r < 3; ++r) {
        float d = u.k.pd[c][p][r]; int s = u.k.pi[c][p][r];
        bool lt0 = d < e0, lt1 = d < e1, lt2 = d < e2;
        e2 = lt1 ? e1 : (lt2 ? d : e2);  j2 = lt1 ? j1 : (lt2 ? s : j2);
        e1 = lt0 ? e0 : (lt1 ? d : e1);  j1 = lt0 ? j0 : (lt1 ? s : j1);
        e0 = lt0 ? d  : e0;              j0 = lt0 ? s : j0;
      }
    float w0 = 1.f / (e0 + KEPS), w1 = 1.f / (e1 + KEPS), w2 = 1.f / (e2 + KEPS);
    float inv = 1.f / (w0 + w1 + w2);
    li[p * 3] = j0; li[p * 3 + 1] = j1; li[p * 3 + 2] = j2;
    lw[p * 3] = w0 * inv; lw[p * 3 + 1] = w1 * inv; lw[p * 3 + 2] = w2 * inv;
  }

  // ---- phase 2: dense [b][c][m] -> X[b*M+m][0:256] bf16 (LDS-tiled transpose)
  int tx = tid & 63, ty = tid >> 6;    // 64 x 4
  for (int ct = 0; ct < 4; ++ct) {
    __syncthreads();                   // first iter: protects union transition
#pragma unroll
    for (int r = 0; r < 16; ++r)
      u.tile[ty * 16 + r][tx] =
          dense[((size_t)b * CD + ct * 64 + ty * 16 + r) * MM + m0 + tx];
    __syncthreads();
#pragma unroll
    for (int r = 0; r < 2; ++r) {
      int lin = r * 256 + tid;         // 512 chunks of 16B
      int ml = lin >> 3, cq = lin & 7;
      short tmp[8];
#pragma unroll
      for (int uu = 0; uu < 8; ++uu) tmp[uu] = f2bf(u.tile[cq * 8 + uu][ml]);
      *(uint4*)(&X[((size_t)b * MM + m0 + ml) * KTOT + ct * 64 + cq * 8]) =
          *(const uint4*)tmp;
    }
  }

  // ---- phase 3: interp -> X[b*M+m][256:768] bf16
#pragma unroll 2
  for (int r = 0; r < 32; ++r) {
    int lin = r * 256 + tid;           // 8192 = 64 m x 128 float4-chunks
    int ml = lin >> 7, c4 = lin & 127;
    int b3 = ml * 3;
    float w0 = lw[b3], w1 = lw[b3 + 1], w2 = lw[b3 + 2];
    const float4 v0 = *(const float4*)(spt + ((size_t)b * SS + li[b3])     * CS + c4 * 4);
    const float4 v1 = *(const float4*)(spt + ((size_t)b * SS + li[b3 + 1]) * CS + c4 * 4);
    const float4 v2 = *(const float4*)(spt + ((size_t)b * SS + li[b3 + 2]) * CS + c4 * 4);
    short t2[4];
    t2[0] = f2bf(w0 * v0.x + w1 * v1.x + w2 * v2.x);
    t2[1] = f2bf(w0 * v0.y + w1 * v1.y + w2 * v2.y);
    t2[2] = f2bf(w0 * v0.z + w1 * v1.z + w2 * v2.z);
    t2[3] = f2bf(w0 * v0.w + w1 * v1.w + w2 * v2.w);
    *(uint2*)(&X[((size_t)b * MM + m0 + ml) * KTOT + CD + c4 * 4]) = *(const uint2*)t2;
  }
}

// ---------------------------------------------------------------- bf16 GEMM
// y[b,o,m] = sum_k W[o,k] * X[b*M+m][k].  NO LDS, NO BARRIERS: both operands
// are K-contiguous, and the 16x16x32 fragment is 8 consecutive k per lane
// (row=lane&15, k=quad*8+j), so fragments load straight from global with one
// dwordx4 (16 rows x 64B dense segments per wave instruction).  The compiler
// fully unrolls K (24 iters) and pipelines loads with fine-grained vmcnt —
// the R1-R3 barrier-drain pathology (all variants ~70-85us, MfmaUtil<=7%) is
// structurally removed.  Block = 4 waves sharing one 64-o tile (W loads are
// identical across waves -> L1 hits), covering 128 m.  XCD swizzle: the 4
// o-tiles of an m-group land on one XCD for X L2-reuse.
__global__ __launch_bounds__(256, 4) void k_gemm(
    const short* __restrict__ wbf, const short* __restrict__ X,
    float* __restrict__ y, float* __restrict__ ssum) {
  int blk = blockIdx.x;            // 1024 blocks
  int x8  = blk & 7;               // XCD id
  int t   = blk >> 3;
  int ot  = t & 3;                 // o-tile 0..3 (64 each)
  int mg  = x8 + (t >> 2) * 8;     // m-group 0..255 — all 4 ot share XCD x8
  int o0  = ot << 6;
  int bm0 = mg << 7;               // 128 m per block (flat b*M+m; 128|4096)
  int tid = threadIdx.x;
  int wv = tid >> 6, lane = tid & 63;
  int lo = lane & 15, quad = lane >> 4;
  int mw = bm0 + wv * 32;          // wave's 32-m stripe

  const short* Wp = wbf + (size_t)(o0 + lo) * KTOT + quad * 8;
  const short* Xp = X + (size_t)(mw + lo) * KTOT + quad * 8;

  f32x4 acc[4][2] = {};            // [o-sub 16][m-sub 16]

#pragma unroll
  for (int k0 = 0; k0 < KTOT; k0 += 32) {
    s16x8 a0 = *(const s16x8*)(Xp + k0);
    s16x8 a1 = *(const s16x8*)(Xp + 16 * KTOT + k0);
    s16x8 b0 = *(const s16x8*)(Wp + k0);
    s16x8 b1 = *(const s16x8*)(Wp + 16 * KTOT + k0);
    s16x8 b2 = *(const s16x8*)(Wp + 32 * KTOT + k0);
    s16x8 b3 = *(const s16x8*)(Wp + 48 * KTOT + k0);
    acc[0][0] = __builtin_amdgcn_mfma_f32_16x16x32_bf16(b0, a0, acc[0][0], 0, 0, 0);
    acc[0][1] = __builtin_amdgcn_mfma_f32_16x16x32_bf16(b0, a1, acc[0][1], 0, 0, 0);
    acc[1][0] = __builtin_amdgcn_mfma_f32_16x16x32_bf16(b1, a0, acc[1][0], 0, 0, 0);
    acc[1][1] = __builtin_amdgcn_mfma_f32_16x16x32_bf16(b1, a1, acc[1][1], 0, 0, 0);
    acc[2][0] = __builtin_amdgcn_mfma_f32_16x16x32_bf16(b2, a0, acc[2][0], 0, 0, 0);
    acc[2][1] = __builtin_amdgcn_mfma_f32_16x16x32_bf16(b2, a1, acc[2][1], 0, 0, 0);
    acc[3][0] = __builtin_amdgcn_mfma_f32_16x16x32_bf16(b3, a0, acc[3][0], 0, 0, 0);
    acc[3][1] = __builtin_amdgcn_mfma_f32_16x16x32_bf16(b3, a1, acc[3][1], 0, 0, 0);
  }

  // ---- epilogue: raw y (pre-BN) into d_out region 0
  int b  = mw >> 12;               // M = 4096
  int mb = mw & (MM - 1);
#pragma unroll
  for (int i = 0; i < 4; ++i) {
    int oo = o0 + i * 16 + quad * 4;
#pragma unroll
    for (int j = 0; j < 2; ++j) {
      int mm2 = mb + j * 16 + lo;
      float* dst = y + ((size_t)b * OC + oo) * MM + mm2;
#pragma unroll
      for (int r = 0; r < 4; ++r) dst[(size_t)r * MM] = acc[i][j][r];
    }
  }
  // ---- fused BN partial stats: per-channel sum/sumsq over this wave's 32 m
#pragma unroll
  for (int i = 0; i < 4; ++i)
#pragma unroll
    for (int r = 0; r < 4; ++r) {
      float s = 0.f, s2 = 0.f;
#pragma unroll
      for (int j = 0; j < 2; ++j) { float v = acc[i][j][r]; s += v; s2 += v * v; }
#pragma unroll
      for (int msk = 1; msk < 16; msk <<= 1) {
        s += __shfl_xor(s, msk); s2 += __shfl_xor(s2, msk);
      }
      if (lo == 0) {
        int oo = o0 + i * 16 + quad * 4 + r;
        atomicAdd(&ssum[oo], s);
        atomicAdd(&ssum[OC + oo], s2);
      }
    }
}

// ---------------------------------------------------------------- BN apply + LeakyReLU
__global__ void k_norm(float* __restrict__ y, const float* __restrict__ ssum,
                       const float* __restrict__ gamma, const float* __restrict__ beta) {
  int i = blockIdx.x * 256 + threadIdx.x;   // float4 index; grid covers exactly
  int o = (i >> 10) & 255;                  // 1024 float4 per (b,o) row
  constexpr float inv = 1.f / (float)(NB * MM);
  float mn = ssum[o] * inv;
  float vr = ssum[OC + o] * inv - mn * mn;
  float a  = rsqrtf(vr + BNEPS) * gamma[o];
  float be = beta[o];
  float4 v = ((const float4*)y)[i];
  float t;
  t = (v.x - mn) * a + be; v.x = t >= 0.f ? t : SLOPE * t;
  t = (v.y - mn) * a + be; v.y = t >= 0.f ? t : SLOPE * t;
  t = (v.z - mn) * a + be; v.z = t >= 0.f ? t : SLOPE * t;
  t = (v.w - mn) * a + be; v.w = t >= 0.f ? t : SLOPE * t;
  ((float4*)y)[i] = v;
}

}  // namespace

extern "C" void kernel_launch(void* const* d_in, const int* in_sizes, int n_in,
                              void* d_out, int out_size, void* d_ws, size_t ws_size,
                              hipStream_t stream) {
  const float* dense = (const float*)d_in[0];
  const int*   didx  = (const int*)d_in[1];
  const float* sp    = (const float*)d_in[2];
  const int*   sidx  = (const int*)d_in[3];
  const float* pcd   = (const float*)d_in[4];
  const float* convw = (const float*)d_in[5];
  const float* gamma = (const float*)d_in[6];
  const float* beta  = (const float*)d_in[7];

  float* y = (float*)d_out;                       // [8][256][4096] raw -> normalized in place
  float* outIdxF = y + (size_t)NB * OC * MM;      // output 1: dense_idx as float

  char* ws = (char*)d_ws;                         // needs ~68.3 MB
  float* spt  = (float*)(ws + OFF_SPT);
  short* wbf  = (short*)(ws + OFF_WBF);
  short* X    = (short*)(ws + OFF_X);
  float* ssum = (float*)(ws + OFF_SSUM);

  k_wcast    <<<(OC * KTOT) / 256, 256, 0, stream>>>(convw, wbf, ssum);
  k_transpose<<<NB * (CS / 32) * (SS / 32), 256, 0, stream>>>(sp, spt);
  k_knn_prep <<<NB * (MM / 64), 256, 0, stream>>>(didx, sidx, pcd, dense, spt, X, outIdxF);
  k_gemm     <<<NB * (MM / 128) * 4, 256, 0, stream>>>(wbf, X, y, ssum);
  k_norm     <<<(NB * OC * MM / 4) / 256, 256, 0, stream>>>(y, ssum, gamma, beta);
}

// Round 7
// 280.180 us; speedup vs baseline: 1.1514x; 1.1514x over previous
//
#include <hip/hip_runtime.h>
#include <hip/hip_bf16.h>
#include <float.h>

#define DEVI __device__ __forceinline__

namespace {

constexpr int NB   = 8;     // batch
constexpr int CD   = 256;   // dense channels
constexpr int CS   = 512;   // sparse channels
constexpr int MM   = 4096;  // dense points
constexpr int SS   = 1024;  // sparse points
constexpr int NN   = 4096;  // pcd points
constexpr int KTOT = 768;   // CD + CS
constexpr int OC   = 256;   // output channels
constexpr float KEPS  = 1e-8f;
constexpr float BNEPS = 1e-5f;
constexpr float SLOPE = 0.2f;

// workspace layout (bytes) — total ~68.3 MB
constexpr size_t OFF_SPT  = 0;                           // float [NB][SS][CS]
constexpr size_t SZ_SPT   = (size_t)NB * SS * CS * 4;    // 16,777,216
constexpr size_t OFF_WBF  = OFF_SPT + SZ_SPT;            // bf16  [OC][KTOT]
constexpr size_t SZ_WBF   = (size_t)OC * KTOT * 2;       // 393,216
constexpr size_t OFF_X    = OFF_WBF + SZ_WBF;            // bf16  [NB*MM][KTOT]
constexpr size_t SZ_X     = (size_t)NB * MM * KTOT * 2;  // 50,331,648
constexpr size_t OFF_SSUM = OFF_X + SZ_X;                // float [2*OC]

typedef __attribute__((ext_vector_type(8))) short s16x8;
typedef __attribute__((ext_vector_type(4))) float f32x4;

// float -> bf16 (RNE), returned as raw short
DEVI short f2bf(float f) {
  union { float f; unsigned u; } c; c.f = f;
  unsigned r = c.u + 0x7fffu + ((c.u >> 16) & 1u);
  return (short)(r >> 16);
}

// ------------------------------------------- conv_w -> bf16, + zero stats acc
__global__ void k_wcast(const float* __restrict__ w, short* __restrict__ wbf,
                        float* __restrict__ ssum) {
  int i = blockIdx.x * 256 + threadIdx.x;   // grid covers OC*KTOT exactly
  if (blockIdx.x < 2) ssum[blockIdx.x * 256 + threadIdx.x] = 0.f;
  wbf[i] = f2bf(w[i]);
}

// ------------------------------------------- sparse_data [b][c][s] -> spt [b][s][c]
__global__ void k_transpose(const float* __restrict__ sp, float* __restrict__ spt) {
  __shared__ float t[32][33];
  int blk = blockIdx.x;                 // 8 * 16 * 32 = 4096 blocks
  int st = blk & 31;
  int ct = (blk >> 5) & 15;
  int b  = blk >> 9;
  int tx = threadIdx.x & 31, ty = threadIdx.x >> 5;   // 32 x 8
  int c0 = ct * 32, s0 = st * 32;
#pragma unroll
  for (int r = 0; r < 32; r += 8)
    t[ty + r][tx] = sp[((size_t)(b * CS + c0 + ty + r)) * SS + s0 + tx];
  __syncthreads();
#pragma unroll
  for (int r = 0; r < 32; r += 8)
    spt[((size_t)(b * SS + s0 + ty + r)) * CS + c0 + tx] = t[tx][ty + r];
}

// ---------------------------------------------------------------- KNN + prep
// One block per (b, 64-m tile), XCD-swizzled: b = blk%8 so each XCD works on
// one batch only -> its 2MB spt slice stays L2-resident for phase-3 gathers.
__global__ __launch_bounds__(256) void k_knn_prep(
    const int* __restrict__ didx, const int* __restrict__ sidx,
    const float* __restrict__ pcd, const float* __restrict__ dense,
    const float* __restrict__ spt, short* __restrict__ X,
    float* __restrict__ outIdxF) {
  __shared__ union {
    struct {
      float4 sxyz[SS];                 // 16 KB candidate coords
      float  pd[4][64][3];             // partial top-3 dists
      int    pi[4][64][3];             // partial top-3 idxs
    } k;
    float tile[64][65];                // dense transpose tile (16.6 KB)
  } u;
  __shared__ int   li[192];            // final top-3 idx per m
  __shared__ float lw[192];            // final weights per m

  int blk = blockIdx.x;                // 512 blocks
  int b   = blk & 7;                   // XCD swizzle: same-b -> same XCD
  int m0  = (blk >> 3) << 6;
  int tid = threadIdx.x;
  const float* pb = pcd + (size_t)b * 3 * NN;

  for (int s = tid; s < SS; s += 256) {
    int si = sidx[b * SS + s];
    u.k.sxyz[s] = make_float4(pb[si], pb[NN + si], pb[2 * NN + si], 0.f);
  }
  int p = tid & 63, chunk = tid >> 6;
  int m = m0 + p;
  int di = didx[b * MM + m];
  float px = pb[di], py = pb[NN + di], pz = pb[2 * NN + di];
  if (chunk == 0) outIdxF[b * MM + m] = (float)di;   // output 1
  __syncthreads();

  {
    float d0 = FLT_MAX, d1 = FLT_MAX, d2 = FLT_MAX;
    int   i0 = 0, i1 = 0, i2 = 0;
    int s0c = chunk << 8;
#pragma unroll 4
    for (int t = 0; t < 256; ++t) {
      int s = s0c + t;
      float4 c = u.k.sxyz[s];
      float dx = c.x - px, dy = c.y - py, dz = c.z - pz;
      float d  = dx * dx + dy * dy + dz * dz;
      bool lt0 = d < d0, lt1 = d < d1, lt2 = d < d2;
      d2 = lt1 ? d1 : (lt2 ? d : d2);  i2 = lt1 ? i1 : (lt2 ? s : i2);
      d1 = lt0 ? d0 : (lt1 ? d : d1);  i1 = lt0 ? i0 : (lt1 ? s : i1);
      d0 = lt0 ? d  : d0;              i0 = lt0 ? s : i0;
    }
    u.k.pd[chunk][p][0] = d0; u.k.pd[chunk][p][1] = d1; u.k.pd[chunk][p][2] = d2;
    u.k.pi[chunk][p][0] = i0; u.k.pi[chunk][p][1] = i1; u.k.pi[chunk][p][2] = i2;
  }
  __syncthreads();

  if (tid < 64) {
    float e0 = FLT_MAX, e1 = FLT_MAX, e2 = FLT_MAX;
    int   j0 = 0, j1 = 0, j2 = 0;
#pragma unroll
    for (int c = 0; c < 4; ++c)
#pragma unroll
      for (int r = 0; r < 3; ++r) {
        float d = u.k.pd[c][p][r]; int s = u.k.pi[c][p][r];
        bool lt0 = d < e0, lt1 = d < e1, lt2 = d < e2;
        e2 = lt1 ? e1 : (lt2 ? d : e2);  j2 = lt1 ? j1 : (lt2 ? s : j2);
        e1 = lt0 ? e0 : (lt1 ? d : e1);  j1 = lt0 ? j0 : (lt1 ? s : j1);
        e0 = lt0 ? d  : e0;              j0 = lt0 ? s : j0;
      }
    float w0 = 1.f / (e0 + KEPS), w1 = 1.f / (e1 + KEPS), w2 = 1.f / (e2 + KEPS);
    float inv = 1.f / (w0 + w1 + w2);
    li[p * 3] = j0; li[p * 3 + 1] = j1; li[p * 3 + 2] = j2;
    lw[p * 3] = w0 * inv; lw[p * 3 + 1] = w1 * inv; lw[p * 3 + 2] = w2 * inv;
  }

  // ---- phase 2: dense [b][c][m] -> X[b*M+m][0:256] bf16 (LDS-tiled transpose)
  int tx = tid & 63, ty = tid >> 6;    // 64 x 4
  for (int ct = 0; ct < 4; ++ct) {
    __syncthreads();                   // first iter: protects union transition
#pragma unroll
    for (int r = 0; r < 16; ++r)
      u.tile[ty * 16 + r][tx] =
          dense[((size_t)b * CD + ct * 64 + ty * 16 + r) * MM + m0 + tx];
    __syncthreads();
#pragma unroll
    for (int r = 0; r < 2; ++r) {
      int lin = r * 256 + tid;         // 512 chunks of 16B
      int ml = lin >> 3, cq = lin & 7;
      short tmp[8];
#pragma unroll
      for (int uu = 0; uu < 8; ++uu) tmp[uu] = f2bf(u.tile[cq * 8 + uu][ml]);
      *(uint4*)(&X[((size_t)b * MM + m0 + ml) * KTOT + ct * 64 + cq * 8]) =
          *(const uint4*)tmp;
    }
  }

  // ---- phase 3: interp -> X[b*M+m][256:768] bf16
#pragma unroll 2
  for (int r = 0; r < 32; ++r) {
    int lin = r * 256 + tid;           // 8192 = 64 m x 128 float4-chunks
    int ml = lin >> 7, c4 = lin & 127;
    int b3 = ml * 3;
    float w0 = lw[b3], w1 = lw[b3 + 1], w2 = lw[b3 + 2];
    const float4 v0 = *(const float4*)(spt + ((size_t)b * SS + li[b3])     * CS + c4 * 4);
    const float4 v1 = *(const float4*)(spt + ((size_t)b * SS + li[b3 + 1]) * CS + c4 * 4);
    const float4 v2 = *(const float4*)(spt + ((size_t)b * SS + li[b3 + 2]) * CS + c4 * 4);
    short t2[4];
    t2[0] = f2bf(w0 * v0.x + w1 * v1.x + w2 * v2.x);
    t2[1] = f2bf(w0 * v0.y + w1 * v1.y + w2 * v2.y);
    t2[2] = f2bf(w0 * v0.z + w1 * v1.z + w2 * v2.z);
    t2[3] = f2bf(w0 * v0.w + w1 * v1.w + w2 * v2.w);
    *(uint2*)(&X[((size_t)b * MM + m0 + ml) * KTOT + CD + c4 * 4]) = *(const uint2*)t2;
  }
}

// ---------------------------------------------------------------- bf16 GEMM
// y[b,o,m] = sum_k W[o,k] * X[b*M+m][k].
// R4 failed because W fragments were reloaded every kc: 6 loads/iter vs a
// 52-VGPR allocation -> compiler serialized every load->MFMA pair (full L2
// latency exposed 144 times/wave).  Fix: hoist W entirely — each wave owns a
// 16-o stripe and preloads all 24 W frags into registers (96 VGPR, static
// indexing via full unroll).  K-loop = 4 independent X loads (4 m-tiles) + 4
// MFMA, explicitly double-buffered; no LDS, no barriers, nothing to drain.
// Block = 4 waves x 16 o = 64 o sharing one 64-m stripe, so the 4 waves' X
// loads are the same addresses -> L1 broadcast.  XCD swizzle: the 4 o-groups
// of an m-stripe land on one XCD -> X pulled from HBM once, L2-served 4x.
__global__ __launch_bounds__(256, 3) void k_gemm(
    const short* __restrict__ wbf, const short* __restrict__ X,
    float* __restrict__ y, float* __restrict__ ssum) {
  int blk = blockIdx.x;            // 2048 blocks
  int x8  = blk & 7;               // XCD id
  int t   = blk >> 3;              // 0..255
  int og  = t & 3;                 // o-group 0..3 (64 each)
  int mg  = (t >> 2) * 8 + x8;     // m-stripe 0..511 — all 4 og share XCD x8
  int o0  = og << 6;
  int bm0 = mg << 6;               // 64 m per block (flat b*M+m; 64|4096)
  int tid = threadIdx.x;
  int wv = tid >> 6, lane = tid & 63;
  int lo = lane & 15, quad = lane >> 4;

  const short* Wp = wbf + (size_t)(o0 + wv * 16 + lo) * KTOT + quad * 8;
  const short* Xp = X + (size_t)(bm0 + lo) * KTOT + quad * 8;

  // ---- preload the wave's entire W stripe: 24 frags, statically indexed
  s16x8 w[24];
#pragma unroll
  for (int kc = 0; kc < 24; ++kc) w[kc] = *(const s16x8*)(Wp + kc * 32);

  f32x4 acc[4] = {};               // 4 m-tiles x (16o x 16m)
  s16x8 xa[4], xb[4];
#pragma unroll
  for (int mt = 0; mt < 4; ++mt)
    xa[mt] = *(const s16x8*)(Xp + (size_t)mt * 16 * KTOT);

#pragma unroll
  for (int kc = 0; kc < 24; ++kc) {
    if (kc + 1 < 24) {
#pragma unroll
      for (int mt = 0; mt < 4; ++mt)
        xb[mt] = *(const s16x8*)(Xp + (size_t)mt * 16 * KTOT + (kc + 1) * 32);
    }
#pragma unroll
    for (int mt = 0; mt < 4; ++mt)
      acc[mt] = __builtin_amdgcn_mfma_f32_16x16x32_bf16(w[kc], xa[mt], acc[mt], 0, 0, 0);
#pragma unroll
    for (int mt = 0; mt < 4; ++mt) xa[mt] = xb[mt];
  }

  // ---- epilogue: raw y (pre-BN) into d_out region 0
  int b  = bm0 >> 12;              // M = 4096
  int mb = bm0 & (MM - 1);
  int oo = o0 + wv * 16 + quad * 4;
#pragma unroll
  for (int mt = 0; mt < 4; ++mt) {
    int mm2 = mb + mt * 16 + lo;
    float* dst = y + ((size_t)b * OC + oo) * MM + mm2;
#pragma unroll
    for (int r = 0; r < 4; ++r) dst[(size_t)r * MM] = acc[mt][r];
  }
  // ---- fused BN partial stats: per-channel sum/sumsq over this block's 64 m
#pragma unroll
  for (int r = 0; r < 4; ++r) {
    float s = 0.f, s2 = 0.f;
#pragma unroll
    for (int mt = 0; mt < 4; ++mt) { float v = acc[mt][r]; s += v; s2 += v * v; }
#pragma unroll
    for (int msk = 1; msk < 16; msk <<= 1) {
      s += __shfl_xor(s, msk); s2 += __shfl_xor(s2, msk);
    }
    if (lo == 0) {
      atomicAdd(&ssum[oo + r], s);
      atomicAdd(&ssum[OC + oo + r], s2);
    }
  }
}

// ---------------------------------------------------------------- BN apply + LeakyReLU
__global__ void k_norm(float* __restrict__ y, const float* __restrict__ ssum,
                       const float* __restrict__ gamma, const float* __restrict__ beta) {
  int i = blockIdx.x * 256 + threadIdx.x;   // float4 index; grid covers exactly
  int o = (i >> 10) & 255;                  // 1024 float4 per (b,o) row
  constexpr float inv = 1.f / (float)(NB * MM);
  float mn = ssum[o] * inv;
  float vr = ssum[OC + o] * inv - mn * mn;
  float a  = rsqrtf(vr + BNEPS) * gamma[o];
  float be = beta[o];
  float4 v = ((const float4*)y)[i];
  float t;
  t = (v.x - mn) * a + be; v.x = t >= 0.f ? t : SLOPE * t;
  t = (v.y - mn) * a + be; v.y = t >= 0.f ? t : SLOPE * t;
  t = (v.z - mn) * a + be; v.z = t >= 0.f ? t : SLOPE * t;
  t = (v.w - mn) * a + be; v.w = t >= 0.f ? t : SLOPE * t;
  ((float4*)y)[i] = v;
}

}  // namespace

extern "C" void kernel_launch(void* const* d_in, const int* in_sizes, int n_in,
                              void* d_out, int out_size, void* d_ws, size_t ws_size,
                              hipStream_t stream) {
  const float* dense = (const float*)d_in[0];
  const int*   didx  = (const int*)d_in[1];
  const float* sp    = (const float*)d_in[2];
  const int*   sidx  = (const int*)d_in[3];
  const float* pcd   = (const float*)d_in[4];
  const float* convw = (const float*)d_in[5];
  const float* gamma = (const float*)d_in[6];
  const float* beta  = (const float*)d_in[7];

  float* y = (float*)d_out;                       // [8][256][4096] raw -> normalized in place
  float* outIdxF = y + (size_t)NB * OC * MM;      // output 1: dense_idx as float

  char* ws = (char*)d_ws;                         // needs ~68.3 MB
  float* spt  = (float*)(ws + OFF_SPT);
  short* wbf  = (short*)(ws + OFF_WBF);
  short* X    = (short*)(ws + OFF_X);
  float* ssum = (float*)(ws + OFF_SSUM);

  k_wcast    <<<(OC * KTOT) / 256, 256, 0, stream>>>(convw, wbf, ssum);
  k_transpose<<<NB * (CS / 32) * (SS / 32), 256, 0, stream>>>(sp, spt);
  k_knn_prep <<<NB * (MM / 64), 256, 0, stream>>>(didx, sidx, pcd, dense, spt, X, outIdxF);
  k_gemm     <<<NB * (MM / 64) * 4, 256, 0, stream>>>(wbf, X, y, ssum);
  k_norm     <<<(NB * OC * MM / 4) / 256, 256, 0, stream>>>(y, ssum, gamma, beta);
}

// Round 8
// 242.667 us; speedup vs baseline: 1.3294x; 1.1546x over previous
//
#include <hip/hip_runtime.h>
#include <hip/hip_bf16.h>
#include <float.h>

#define DEVI __device__ __forceinline__

namespace {

constexpr int NB   = 8;     // batch
constexpr int CD   = 256;   // dense channels (= dense K)
constexpr int CS   = 512;   // sparse channels
constexpr int MM   = 4096;  // dense points
constexpr int SS   = 1024;  // sparse points
constexpr int NN   = 4096;  // pcd points
constexpr int KTOT = 768;   // CD + CS (conv_w row length)
constexpr int OC   = 256;   // output channels
constexpr float KEPS  = 1e-8f;
constexpr float BNEPS = 1e-5f;
constexpr float SLOPE = 0.2f;

// workspace layout (bytes) — total ~34.7 MB
constexpr size_t OFF_SPTB = 0;                            // bf16 [NB][SS][CS]
constexpr size_t SZ_SPTB  = (size_t)NB * SS * CS * 2;     // 8,388,608
constexpr size_t OFF_WBF  = OFF_SPTB + SZ_SPTB;           // bf16 [OC][KTOT]
constexpr size_t SZ_WBF   = (size_t)OC * KTOT * 2;        // 393,216
constexpr size_t OFF_XD   = OFF_WBF + SZ_WBF;             // bf16 [NB*MM][CD]
constexpr size_t SZ_XD    = (size_t)NB * MM * CD * 2;     // 16,777,216
constexpr size_t OFF_ZT   = OFF_XD + SZ_XD;               // f32  [NB][SS][OC]
constexpr size_t SZ_ZT    = (size_t)NB * SS * OC * 4;     // 8,388,608
constexpr size_t OFF_IDX3 = OFF_ZT + SZ_ZT;               // int  [NB*MM*3]
constexpr size_t SZ_IDX3  = (size_t)NB * MM * 3 * 4;      // 393,216
constexpr size_t OFF_W3   = OFF_IDX3 + SZ_IDX3;           // f32  [NB*MM*3]
constexpr size_t OFF_SSUM = OFF_W3 + SZ_IDX3;             // f32  [2*OC]

typedef __attribute__((ext_vector_type(8))) short s16x8;
typedef __attribute__((ext_vector_type(4))) float f32x4;

// float -> bf16 (RNE), returned as raw short
DEVI short f2bf(float f) {
  union { float f; unsigned u; } c; c.f = f;
  unsigned r = c.u + 0x7fffu + ((c.u >> 16) & 1u);
  return (short)(r >> 16);
}

// ------------------------------------------- conv_w -> bf16, + zero stats acc
__global__ void k_wcast(const float* __restrict__ w, short* __restrict__ wbf,
                        float* __restrict__ ssum) {
  int i = blockIdx.x * 256 + threadIdx.x;   // grid covers OC*KTOT exactly
  if (blockIdx.x < 2) ssum[blockIdx.x * 256 + threadIdx.x] = 0.f;
  wbf[i] = f2bf(w[i]);
}

// --------------------------- sparse_data [b][c][s] f32 -> sptb [b][s][c] bf16
__global__ void k_transb(const float* __restrict__ sp, short* __restrict__ sptb) {
  __shared__ float t[32][33];
  int blk = blockIdx.x;                 // 8 * 16 * 32 = 4096 blocks
  int st = blk & 31;
  int ct = (blk >> 5) & 15;
  int b  = blk >> 9;
  int tx = threadIdx.x & 31, ty = threadIdx.x >> 5;   // 32 x 8
  int c0 = ct * 32, s0 = st * 32;
#pragma unroll
  for (int r = 0; r < 32; r += 8)
    t[ty + r][tx] = sp[((size_t)(b * CS + c0 + ty + r)) * SS + s0 + tx];
  __syncthreads();
#pragma unroll
  for (int r = 0; r < 32; r += 8)
    sptb[((size_t)(b * SS + s0 + ty + r)) * CS + c0 + tx] = f2bf(t[tx][ty + r]);
}

// ---------------------------------------------------------------- KNN + Xd prep
// One block per (b, 64-m tile), b = blk%8 (XCD-local batch).
// Phase 1: top-3 KNN (lane-per-point) -> idx3/w3 global.
// Phase 2: dense transpose+cast -> Xd[b*M+m][0:256] bf16.
__global__ __launch_bounds__(256) void k_knn_prep(
    const int* __restrict__ didx, const int* __restrict__ sidx,
    const float* __restrict__ pcd, const float* __restrict__ dense,
    short* __restrict__ Xd, int* __restrict__ idx3, float* __restrict__ w3,
    float* __restrict__ outIdxF) {
  __shared__ union {
    struct {
      float4 sxyz[SS];                 // 16 KB candidate coords
      float  pd[4][64][3];             // partial top-3 dists
      int    pi[4][64][3];             // partial top-3 idxs
    } k;
    float tile[64][65];                // dense transpose tile (16.6 KB)
  } u;

  int blk = blockIdx.x;                // 512 blocks
  int b   = blk & 7;                   // XCD swizzle: same-b -> same XCD
  int m0  = (blk >> 3) << 6;
  int tid = threadIdx.x;
  const float* pb = pcd + (size_t)b * 3 * NN;

  for (int s = tid; s < SS; s += 256) {
    int si = sidx[b * SS + s];
    u.k.sxyz[s] = make_float4(pb[si], pb[NN + si], pb[2 * NN + si], 0.f);
  }
  int p = tid & 63, chunk = tid >> 6;
  int m = m0 + p;
  int di = didx[b * MM + m];
  float px = pb[di], py = pb[NN + di], pz = pb[2 * NN + di];
  if (chunk == 0) outIdxF[b * MM + m] = (float)di;   // output 1
  __syncthreads();

  {
    float d0 = FLT_MAX, d1 = FLT_MAX, d2 = FLT_MAX;
    int   i0 = 0, i1 = 0, i2 = 0;
    int s0c = chunk << 8;
#pragma unroll 4
    for (int t = 0; t < 256; ++t) {
      int s = s0c + t;
      float4 c = u.k.sxyz[s];
      float dx = c.x - px, dy = c.y - py, dz = c.z - pz;
      float d  = dx * dx + dy * dy + dz * dz;
      bool lt0 = d < d0, lt1 = d < d1, lt2 = d < d2;
      d2 = lt1 ? d1 : (lt2 ? d : d2);  i2 = lt1 ? i1 : (lt2 ? s : i2);
      d1 = lt0 ? d0 : (lt1 ? d : d1);  i1 = lt0 ? i0 : (lt1 ? s : i1);
      d0 = lt0 ? d  : d0;              i0 = lt0 ? s : i0;
    }
    u.k.pd[chunk][p][0] = d0; u.k.pd[chunk][p][1] = d1; u.k.pd[chunk][p][2] = d2;
    u.k.pi[chunk][p][0] = i0; u.k.pi[chunk][p][1] = i1; u.k.pi[chunk][p][2] = i2;
  }
  __syncthreads();

  if (tid < 64) {
    float e0 = FLT_MAX, e1 = FLT_MAX, e2 = FLT_MAX;
    int   j0 = 0, j1 = 0, j2 = 0;
#pragma unroll
    for (int c = 0; c < 4; ++c)
#pragma unroll
      for (int r = 0; r < 3; ++r) {
        float d = u.k.pd[c][p][r]; int s = u.k.pi[c][p][r];
        bool lt0 = d < e0, lt1 = d < e1, lt2 = d < e2;
        e2 = lt1 ? e1 : (lt2 ? d : e2);  j2 = lt1 ? j1 : (lt2 ? s : j2);
        e1 = lt0 ? e0 : (lt1 ? d : e1);  j1 = lt0 ? j0 : (lt1 ? s : j1);
        e0 = lt0 ? d  : e0;              j0 = lt0 ? s : j0;
      }
    float w0 = 1.f / (e0 + KEPS), w1 = 1.f / (e1 + KEPS), w2 = 1.f / (e2 + KEPS);
    float inv = 1.f / (w0 + w1 + w2);
    int base = (b * MM + m) * 3;
    idx3[base] = j0; idx3[base + 1] = j1; idx3[base + 2] = j2;
    w3[base] = w0 * inv; w3[base + 1] = w1 * inv; w3[base + 2] = w2 * inv;
  }

  // ---- phase 2: dense [b][c][m] -> Xd[b*M+m][0:256] bf16 (LDS-tiled transpose)
  int tx = tid & 63, ty = tid >> 6;    // 64 x 4
  for (int ct = 0; ct < 4; ++ct) {
    __syncthreads();                   // first iter: protects union transition
#pragma unroll
    for (int r = 0; r < 16; ++r)
      u.tile[ty * 16 + r][tx] =
          dense[((size_t)b * CD + ct * 64 + ty * 16 + r) * MM + m0 + tx];
    __syncthreads();
#pragma unroll
    for (int r = 0; r < 2; ++r) {
      int lin = r * 256 + tid;         // 512 chunks of 16B
      int ml = lin >> 3, cq = lin & 7;
      short tmp[8];
#pragma unroll
      for (int uu = 0; uu < 8; ++uu) tmp[uu] = f2bf(u.tile[cq * 8 + uu][ml]);
      *(uint4*)(&Xd[((size_t)b * MM + m0 + ml) * CD + ct * 64 + cq * 8]) =
          *(const uint4*)tmp;
    }
  }
}

// ---------------------------------------------------------------- Z GEMM
// ZT[b][s][o] = sum_c sptb[b][s][c] * Ws[o][c]   (Ws = conv_w cols 256..768)
// wave: 16-o stripe (A, preloaded 16 frags) x 4 s-tiles (B, streamed).
// Block = 4 waves x 16 o = 64 o over one 64-s stripe; XCD = batch.
__global__ __launch_bounds__(256, 3) void k_zgemm(
    const short* __restrict__ wbf, const short* __restrict__ sptb,
    float* __restrict__ ZT) {
  int blk = blockIdx.x;            // 512 blocks
  int b   = blk & 7;               // XCD = batch
  int t   = blk >> 3;              // 0..63
  int og  = t & 3;                 // 64-o group
  int sgi = t >> 2;                // 0..15 s-stripe within batch
  int o0  = og << 6;
  int s0  = b * SS + sgi * 64;     // flat b*SS + s
  int tid = threadIdx.x;
  int wv = tid >> 6, lane = tid & 63;
  int lo = lane & 15, quad = lane >> 4;

  const short* Wp = wbf + (size_t)(o0 + wv * 16 + lo) * KTOT + CD + quad * 8;
  const short* Sp = sptb + (size_t)(s0 + lo) * CS + quad * 8;

  s16x8 w[16];
#pragma unroll
  for (int kc = 0; kc < 16; ++kc) w[kc] = *(const s16x8*)(Wp + kc * 32);

  f32x4 acc[4] = {};
  s16x8 xa[4], xb[4];
#pragma unroll
  for (int st = 0; st < 4; ++st)
    xa[st] = *(const s16x8*)(Sp + (size_t)st * 16 * CS);

#pragma unroll
  for (int kc = 0; kc < 16; ++kc) {
    if (kc + 1 < 16) {
#pragma unroll
      for (int st = 0; st < 4; ++st)
        xb[st] = *(const s16x8*)(Sp + (size_t)st * 16 * CS + (kc + 1) * 32);
    }
#pragma unroll
    for (int st = 0; st < 4; ++st)
      acc[st] = __builtin_amdgcn_mfma_f32_16x16x32_bf16(w[kc], xa[st], acc[st], 0, 0, 0);
#pragma unroll
    for (int st = 0; st < 4; ++st) xa[st] = xb[st];
  }

  // store: lane holds o = o0+wv*16+quad*4+r (r=0..3 contiguous) at row s0+st*16+lo
  int oo = o0 + wv * 16 + quad * 4;
#pragma unroll
  for (int st = 0; st < 4; ++st)
    *(f32x4*)(ZT + (size_t)(s0 + st * 16 + lo) * OC + oo) = acc[st];
}

// ---------------------------------------------------------------- Y GEMM + combine + stats
// y[b,o,m] = sum_{k<256} Wd[o,k]*Xd[b*M+m][k]  +  sum_j w3[m,j]*ZT[b][idx3[m,j]][o]
// K=256 -> 8 iters only; no LDS, no barriers.  wave: 16-o stripe (Wd preload,
// 8 frags) x 4 m-tiles.  Block = 64 o x 64 m; XCD = batch so ZT[b] (1MB),
// idx3/w3[b] are XCD-L2-resident and Xd stripes are shared by the 4 o-groups.
// BN batch stats fused (atomics on ssum).
__global__ __launch_bounds__(256, 4) void k_ygemm(
    const short* __restrict__ wbf, const short* __restrict__ Xd,
    const int* __restrict__ idx3, const float* __restrict__ w3,
    const float* __restrict__ ZT, float* __restrict__ y,
    float* __restrict__ ssum) {
  int blk = blockIdx.x;            // 2048 blocks
  int b   = blk & 7;               // XCD = batch
  int t   = blk >> 3;              // 0..255
  int og  = t & 3;                 // 64-o group
  int mi  = t >> 2;                // 0..63 m-stripe within batch
  int o0  = og << 6;
  int m0  = mi << 6;
  int bm0 = b * MM + m0;
  int tid = threadIdx.x;
  int wv = tid >> 6, lane = tid & 63;
  int lo = lane & 15, quad = lane >> 4;

  const short* Wp = wbf + (size_t)(o0 + wv * 16 + lo) * KTOT + quad * 8;
  const short* Xp = Xd + (size_t)(bm0 + lo) * CD + quad * 8;

  s16x8 w[8];
#pragma unroll
  for (int kc = 0; kc < 8; ++kc) w[kc] = *(const s16x8*)(Wp + kc * 32);

  f32x4 acc[4] = {};
  s16x8 xa[4], xb[4];
#pragma unroll
  for (int mt = 0; mt < 4; ++mt)
    xa[mt] = *(const s16x8*)(Xp + (size_t)mt * 16 * CD);

#pragma unroll
  for (int kc = 0; kc < 8; ++kc) {
    if (kc + 1 < 8) {
#pragma unroll
      for (int mt = 0; mt < 4; ++mt)
        xb[mt] = *(const s16x8*)(Xp + (size_t)mt * 16 * CD + (kc + 1) * 32);
    }
#pragma unroll
    for (int mt = 0; mt < 4; ++mt)
      acc[mt] = __builtin_amdgcn_mfma_f32_16x16x32_bf16(w[kc], xa[mt], acc[mt], 0, 0, 0);
#pragma unroll
    for (int mt = 0; mt < 4; ++mt) xa[mt] = xb[mt];
  }

  // ---- combine: interp contribution via ZT gathers (L2-resident, 1MB/batch)
  int oo = o0 + wv * 16 + quad * 4;
  const float* ZTb = ZT + (size_t)b * SS * OC + oo;
#pragma unroll
  for (int mt = 0; mt < 4; ++mt) {
    int gi = (bm0 + mt * 16 + lo) * 3;
#pragma unroll
    for (int j = 0; j < 3; ++j) {
      int   idx = idx3[gi + j];
      float wj  = w3[gi + j];
      f32x4 z = *(const f32x4*)(ZTb + (size_t)idx * OC);
#pragma unroll
      for (int r = 0; r < 4; ++r) acc[mt][r] += wj * z[r];
    }
  }

  // ---- epilogue: raw y (pre-BN) into d_out region 0
#pragma unroll
  for (int mt = 0; mt < 4; ++mt) {
    int mm2 = m0 + mt * 16 + lo;
    float* dst = y + ((size_t)b * OC + oo) * MM + mm2;
#pragma unroll
    for (int r = 0; r < 4; ++r) dst[(size_t)r * MM] = acc[mt][r];
  }
  // ---- fused BN partial stats over this block's 64 m
#pragma unroll
  for (int r = 0; r < 4; ++r) {
    float s = 0.f, s2 = 0.f;
#pragma unroll
    for (int mt = 0; mt < 4; ++mt) { float v = acc[mt][r]; s += v; s2 += v * v; }
#pragma unroll
    for (int msk = 1; msk < 16; msk <<= 1) {
      s += __shfl_xor(s, msk); s2 += __shfl_xor(s2, msk);
    }
    if (lo == 0) {
      atomicAdd(&ssum[oo + r], s);
      atomicAdd(&ssum[OC + oo + r], s2);
    }
  }
}

// ---------------------------------------------------------------- BN apply + LeakyReLU
__global__ void k_norm(float* __restrict__ y, const float* __restrict__ ssum,
                       const float* __restrict__ gamma, const float* __restrict__ beta) {
  int i = blockIdx.x * 256 + threadIdx.x;   // float4 index; grid covers exactly
  int o = (i >> 10) & 255;                  // 1024 float4 per (b,o) row
  constexpr float inv = 1.f / (float)(NB * MM);
  float mn = ssum[o] * inv;
  float vr = ssum[OC + o] * inv - mn * mn;
  float a  = rsqrtf(vr + BNEPS) * gamma[o];
  float be = beta[o];
  float4 v = ((const float4*)y)[i];
  float t;
  t = (v.x - mn) * a + be; v.x = t >= 0.f ? t : SLOPE * t;
  t = (v.y - mn) * a + be; v.y = t >= 0.f ? t : SLOPE * t;
  t = (v.z - mn) * a + be; v.z = t >= 0.f ? t : SLOPE * t;
  t = (v.w - mn) * a + be; v.w = t >= 0.f ? t : SLOPE * t;
  ((float4*)y)[i] = v;
}

}  // namespace

extern "C" void kernel_launch(void* const* d_in, const int* in_sizes, int n_in,
                              void* d_out, int out_size, void* d_ws, size_t ws_size,
                              hipStream_t stream) {
  const float* dense = (const float*)d_in[0];
  const int*   didx  = (const int*)d_in[1];
  const float* sp    = (const float*)d_in[2];
  const int*   sidx  = (const int*)d_in[3];
  const float* pcd   = (const float*)d_in[4];
  const float* convw = (const float*)d_in[5];
  const float* gamma = (const float*)d_in[6];
  const float* beta  = (const float*)d_in[7];

  float* y = (float*)d_out;                       // [8][256][4096] raw -> normalized in place
  float* outIdxF = y + (size_t)NB * OC * MM;      // output 1: dense_idx as float

  char* ws = (char*)d_ws;                         // needs ~34.7 MB
  short* sptb = (short*)(ws + OFF_SPTB);
  short* wbf  = (short*)(ws + OFF_WBF);
  short* Xd   = (short*)(ws + OFF_XD);
  float* ZT   = (float*)(ws + OFF_ZT);
  int*   idx3 = (int*)(ws + OFF_IDX3);
  float* w3   = (float*)(ws + OFF_W3);
  float* ssum = (float*)(ws + OFF_SSUM);

  k_wcast    <<<(OC * KTOT) / 256, 256, 0, stream>>>(convw, wbf, ssum);
  k_transb   <<<NB * (CS / 32) * (SS / 32), 256, 0, stream>>>(sp, sptb);
  k_knn_prep <<<NB * (MM / 64), 256, 0, stream>>>(didx, sidx, pcd, dense, Xd, idx3, w3, outIdxF);
  k_zgemm    <<<NB * 4 * (SS / 64), 256, 0, stream>>>(wbf, sptb, ZT);
  k_ygemm    <<<NB * 4 * (MM / 64), 256, 0, stream>>>(wbf, Xd, idx3, w3, ZT, y, ssum);
  k_norm     <<<(NB * OC * MM / 4) / 256, 256, 0, stream>>>(y, ssum, gamma, beta);
}